// Round 5
// baseline (166.249 us; speedup 1.0000x reference)
//
#include <hip/hip_runtime.h>
#include <stdint.h>

#define NB 4
#define CC 256
#define C16 16
#define HH 64
#define WW 64
#define NN 4096

typedef __attribute__((ext_vector_type(8))) short short8;
typedef __attribute__((ext_vector_type(4))) float floatx4;
typedef __attribute__((ext_vector_type(16))) float floatx16;

#if __has_builtin(__builtin_amdgcn_exp2f)
#define EXP2(x) __builtin_amdgcn_exp2f(x)
#else
#define EXP2(x) exp2f(x)
#endif

__device__ __forceinline__ unsigned short f2bf(float f) {
    union { float f; unsigned u; } v; v.f = f;
    unsigned r = v.u + 0x7fffu + ((v.u >> 16) & 1u);
    return (unsigned short)(r >> 16);
}
__device__ __forceinline__ float bf2f(unsigned short h) {
    union { unsigned u; float f; } v; v.u = (unsigned)h << 16;
    return v.f;
}

// async global->LDS, 16B per lane; LDS dest is wave-uniform base + lane*16 (HW rule)
__device__ __forceinline__ void gll16(const unsigned short* g, char* l) {
    __builtin_amdgcn_global_load_lds(
        (const __attribute__((address_space(1))) void*)g,
        (__attribute__((address_space(3))) void*)l, 16, 0, 0);
}

// Fragment-major layouts (frag = 32 rows x 16 k = 64 lanes x 8 bf16 = 1KB):
//   qb/kb: frag f = b*128 + (n>>5); addr = f*512 + (n&31 + 32*(o>>3))*8 + (o&7)
//   vb:    frag f = (b*8 + (c>>5))*256 + (n>>4); addr = f*512 + (c&31 + 32*((n>>3)&1))*8 + (n&7)

// ========== K1: cast x->xT bf16 [b][n][c] (vectorized); cast wv/wq/wk; zero nu2 ==========
__global__ __launch_bounds__(256) void prep_kernel(
        const float* __restrict__ x, const float* __restrict__ wv,
        const float* __restrict__ wq, const float* __restrict__ wk,
        unsigned short* __restrict__ xT, unsigned short* __restrict__ wvb,
        unsigned short* __restrict__ wqkb, float* __restrict__ nu2) {
    int bid = blockIdx.x;
    if (bid < 1024) {
        __shared__ float tile_t[64][65];   // [n-local][c-local], pad 65: 2-way free
        int nt = bid & 63, ct = (bid >> 6) & 3, b = bid >> 8;
        int n0 = nt * 64, c0 = ct * 64;
        int tid = threadIdx.x;
        int rg = tid >> 4, f = tid & 15;
        const float* xb = x + ((size_t)b * CC + c0) * NN + n0;
#pragma unroll
        for (int p = 0; p < 4; ++p) {
            int c = p * 16 + rg;
            float4 v = *(const float4*)(xb + (size_t)c * NN + f * 4);
            tile_t[f * 4 + 0][c] = v.x;
            tile_t[f * 4 + 1][c] = v.y;
            tile_t[f * 4 + 2][c] = v.z;
            tile_t[f * 4 + 3][c] = v.w;
        }
        __syncthreads();
        unsigned short* xtb = xT + ((size_t)b * NN + n0) * CC + c0;
#pragma unroll
        for (int p = 0; p < 4; ++p) {
            int n = p * 16 + rg;
            ushort4 st;
            st.x = f2bf(tile_t[n][f * 4 + 0]);
            st.y = f2bf(tile_t[n][f * 4 + 1]);
            st.z = f2bf(tile_t[n][f * 4 + 2]);
            st.w = f2bf(tile_t[n][f * 4 + 3]);
            *(ushort4*)(xtb + (size_t)n * CC + f * 4) = st;
        }
    } else {
        int idx = (bid - 1024) * 256 + threadIdx.x;
        if (bid == 1024 && threadIdx.x < 128) nu2[threadIdx.x] = 0.f;
        if (idx < 16384) {
            float4 v = *(const float4*)(wv + idx * 4);
            ushort4 o;
            o.x = f2bf(v.x); o.y = f2bf(v.y); o.z = f2bf(v.z); o.w = f2bf(v.w);
            *(ushort4*)(wvb + idx * 4) = o;
        } else if (idx < 16384 + 6144) {
            int base = (idx - 16384) * 4;
#pragma unroll
            for (int u = 0; u < 4; ++u) {
                int e = base + u;
                int t = e / 12288;
                int i = e - t * 12288;
                int tap = i >> 12, o = (i >> 8) & 15, c = i & 255;
                const float* src = t ? wk : wq;
                wqkb[e] = f2bf(src[o * 768 + c * 3 + tap]);
            }
        }
    }
}

// ========== K2: conv_v (0..511) + conv_qk w/ FRN-ssq atomics (512..767) ==========
__global__ __launch_bounds__(256) void conv_kernel(
        const unsigned short* __restrict__ xT, const unsigned short* __restrict__ wvb,
        const unsigned short* __restrict__ wqkb, const float* __restrict__ bv,
        const float* __restrict__ bq, const float* __restrict__ bk,
        unsigned short* __restrict__ vb, unsigned short* __restrict__ qrawh,
        unsigned short* __restrict__ krawh, float* __restrict__ nu2) {
    int bid = blockIdx.x;
    int tid = threadIdx.x;
    int wv_ = tid >> 6, lane = tid & 63;
    int q16 = lane >> 4, c16 = lane & 15;
    if (bid < 512) {
        int ntile = bid & 63, b = (bid >> 6) & 3, ch = bid >> 8;
        int n0 = ntile * 64;
        int cb = ch * 128 + wv_ * 32;
        floatx4 fzero = {0.f, 0.f, 0.f, 0.f};
        floatx4 acc[2][4];
        for (int ct = 0; ct < 2; ++ct)
            for (int nt = 0; nt < 4; ++nt) acc[ct][nt] = fzero;
        const unsigned short* xb = xT + ((size_t)b * NN + n0) * CC;
        for (int kc = 0; kc < 8; ++kc) {
            int ko = kc * 32 + q16 * 8;
            short8 a0 = *(const short8*)(wvb + (size_t)(cb + c16) * CC + ko);
            short8 a1 = *(const short8*)(wvb + (size_t)(cb + 16 + c16) * CC + ko);
            short8 bf[4];
#pragma unroll
            for (int nt = 0; nt < 4; ++nt)
                bf[nt] = *(const short8*)(xb + (size_t)(nt * 16 + c16) * CC + ko);
#pragma unroll
            for (int nt = 0; nt < 4; ++nt) {
                acc[0][nt] = __builtin_amdgcn_mfma_f32_16x16x32_bf16(bf[nt], a0, acc[0][nt], 0, 0, 0);
                acc[1][nt] = __builtin_amdgcn_mfma_f32_16x16x32_bf16(bf[nt], a1, acc[1][nt], 0, 0, 0);
            }
        }
        // C: row = q16*4+r -> n-local, col = c16 -> c-local. ushort4 frag-major stores.
        float bv0 = bv[cb + c16], bv1 = bv[cb + 16 + c16];
        int off = 32 * 8 * (q16 >> 1) + (q16 & 1) * 4 + c16 * 8;
#pragma unroll
        for (int ct = 0; ct < 2; ++ct) {
            float bvv = ct ? bv1 : bv0;
#pragma unroll
            for (int nt = 0; nt < 4; ++nt) {
                size_t fb = (((size_t)b * 8 + ch * 4 + wv_) * 256 + (n0 >> 4) + nt) * 512;
                ushort4 st;
                st.x = f2bf(acc[ct][nt][0] + bvv);
                st.y = f2bf(acc[ct][nt][1] + bvv);
                st.z = f2bf(acc[ct][nt][2] + bvv);
                st.w = f2bf(acc[ct][nt][3] + bvv);
                *(ushort4*)(vb + fb + off + ct * 16 * 8) = st;
            }
        }
    } else {
        int cv = bid - 512;
        int nb2 = cv & 63, b = cv >> 6;
        int nl = nb2 * 64 + wv_ * 16 + c16;     // load-n (A-frag m index)
        int h = nl >> 6, w = nl & 63;
        bool vm1 = (w != 0), vp1 = (w != 63);
        bool vm64 = (h != 0), vp64 = (h != 63);
        short8 zero8 = {0, 0, 0, 0, 0, 0, 0, 0};
        floatx4 accq = {0.f, 0.f, 0.f, 0.f}, acck = {0.f, 0.f, 0.f, 0.f};
        const unsigned short* xb = xT + (size_t)b * NN * CC;
        const unsigned short* wrow = wqkb + c16 * 256;
        for (int kc = 0; kc < 8; ++kc) {
            int ko = kc * 32 + q16 * 8;
            short8 b0 = *(const short8*)(xb + (size_t)nl * CC + ko);
            short8 bm1 = vm1 ? *(const short8*)(xb + (size_t)(nl - 1) * CC + ko) : zero8;
            short8 bp1 = vp1 ? *(const short8*)(xb + (size_t)(nl + 1) * CC + ko) : zero8;
            short8 bm64 = vm64 ? *(const short8*)(xb + (size_t)(nl - 64) * CC + ko) : zero8;
            short8 bp64 = vp64 ? *(const short8*)(xb + (size_t)(nl + 64) * CC + ko) : zero8;
            short8 aq0 = *(const short8*)(wrow + 0 * 4096 + ko);
            short8 aq1 = *(const short8*)(wrow + 1 * 4096 + ko);
            short8 aq2 = *(const short8*)(wrow + 2 * 4096 + ko);
            short8 ak0 = *(const short8*)(wrow + 12288 + 0 * 4096 + ko);
            short8 ak1 = *(const short8*)(wrow + 12288 + 1 * 4096 + ko);
            short8 ak2 = *(const short8*)(wrow + 12288 + 2 * 4096 + ko);
            accq = __builtin_amdgcn_mfma_f32_16x16x32_bf16(bm1, aq0, accq, 0, 0, 0);
            accq = __builtin_amdgcn_mfma_f32_16x16x32_bf16(b0, aq1, accq, 0, 0, 0);
            accq = __builtin_amdgcn_mfma_f32_16x16x32_bf16(bp1, aq2, accq, 0, 0, 0);
            acck = __builtin_amdgcn_mfma_f32_16x16x32_bf16(bm64, ak0, acck, 0, 0, 0);
            acck = __builtin_amdgcn_mfma_f32_16x16x32_bf16(b0, ak1, acck, 0, 0, 0);
            acck = __builtin_amdgcn_mfma_f32_16x16x32_bf16(bp64, ak2, acck, 0, 0, 0);
        }
        // C: row = q16*4+r -> n, col = c16 -> o. bf16 ushort4 stores.
        int nst = nb2 * 64 + wv_ * 16 + q16 * 4;
        float bqv = bq[c16], bkv = bk[c16];
        ushort4 sq4, sk4;
        float ssq = 0.f, ssk = 0.f;
        {
            float vq0 = accq[0] + bqv, vq1 = accq[1] + bqv, vq2 = accq[2] + bqv, vq3 = accq[3] + bqv;
            float vk0 = acck[0] + bkv, vk1 = acck[1] + bkv, vk2 = acck[2] + bkv, vk3 = acck[3] + bkv;
            sq4.x = f2bf(vq0); sq4.y = f2bf(vq1); sq4.z = f2bf(vq2); sq4.w = f2bf(vq3);
            sk4.x = f2bf(vk0); sk4.y = f2bf(vk1); sk4.z = f2bf(vk2); sk4.w = f2bf(vk3);
            ssq = vq0 * vq0 + vq1 * vq1 + vq2 * vq2 + vq3 * vq3;
            ssk = vk0 * vk0 + vk1 * vk1 + vk2 * vk2 + vk3 * vk3;
        }
        *(ushort4*)(qrawh + (size_t)(b * C16 + c16) * NN + nst) = sq4;
        *(ushort4*)(krawh + (size_t)(b * C16 + c16) * NN + nst) = sk4;
        ssq += __shfl_xor(ssq, 16, 64);
        ssq += __shfl_xor(ssq, 32, 64);
        ssk += __shfl_xor(ssk, 16, 64);
        ssk += __shfl_xor(ssk, 32, 64);
        if (lane < 16) {
            atomicAdd(nu2 + b * C16 + lane, ssq);
            atomicAdd(nu2 + 64 + b * C16 + lane, ssk);
        }
    }
}

// ========== K3: FRN + Mish (bf16 input), frag-major out; 512 blocks, 4 ch/thread ==========
// q additionally scaled by log2(e) so attention can use exp2.
__global__ __launch_bounds__(256) void frn_mish_kernel(
        const unsigned short* __restrict__ qrawh, const unsigned short* __restrict__ krawh,
        const float* __restrict__ nu2, const float* __restrict__ eps_q,
        const float* __restrict__ eps_k, unsigned short* __restrict__ qb,
        unsigned short* __restrict__ kb) {
    int blk = blockIdx.x;                 // 512 = tensor(2) x b(4) x nchunk(64)
    int tensor = blk >> 8;
    int b = (blk >> 6) & 3;
    int nch = blk & 63;
    const unsigned short* raw = tensor ? krawh : qrawh;
    const float* eps = tensor ? eps_k : eps_q;
    unsigned short* outp = tensor ? kb : qb;
    const float* nu = nu2 + tensor * 64 + b * C16;
    float scale = tensor ? 1.0f : 1.44269504f;
    int n = nch * 64 + (threadIdx.x & 63);
    int oq = threadIdx.x >> 6;            // 0..3 -> channels oq*4..oq*4+3
    ushort4 pk4;
#pragma unroll
    for (int i = 0; i < 4; ++i) {
        int o = oq * 4 + i;
        float r = bf2f(raw[(size_t)(b * C16 + o) * NN + n]);
        float v = r * rsqrtf(nu[o] * (1.f / (float)NN) + fabsf(eps[o]));
        float sp = fmaxf(v, 0.f) + log1pf(expf(-fabsf(v)));   // stable softplus
        float m = v * tanhf(sp) * scale;
        ((unsigned short*)&pk4)[i] = f2bf(m);
    }
    size_t base = ((size_t)b * 128 + (n >> 5)) * 512 + (size_t)(n & 31) * 8
                + (size_t)(oq >> 1) * 256 + (oq & 1) * 4;
    *(ushort4*)(outp + base) = pk4;
}

// exp2 (NO shift — softmax is shift-invariant; S range fits f32/bf16 exponent span).
// Half-pack: 8 score elements (half of a floatx16) -> one bf16 A-frag word via
// v_permlane32_swap_b32. h must be a literal (inlined). Numerically identical to
// the old pack_p0 (same ops, same order per element).
__device__ __forceinline__ void pack_half(
        const floatx16& sc, int h, short8* A, float* lsum) {
    unsigned pk[4];
    float ls = 0.f;
#pragma unroll
    for (int p = 0; p < 4; ++p) {
        float e0 = EXP2(sc[8 * h + 2 * p]);
        float e1 = EXP2(sc[8 * h + 2 * p + 1]);
        ls += e0 + e1;
        pk[p] = __builtin_amdgcn_perm(__float_as_uint(e1), __float_as_uint(e0), 0x07060302u);
    }
    *lsum += ls;
    asm("v_permlane32_swap_b32 %0, %1" : "+v"(pk[0]), "+v"(pk[2]));
    asm("v_permlane32_swap_b32 %0, %1" : "+v"(pk[1]), "+v"(pk[3]));
    union { unsigned u[4]; short8 s; } a;
    a.u[0] = pk[0]; a.u[1] = pk[1]; a.u[2] = pk[2]; a.u[3] = pk[3];
    *A = a.s;
}

// ========== K4: attention, j=64 c=128 per block, LDS-staged V (dbuf), counted vmcnt ==========
// grid 512: cs = id&1 (128-c), b = (id>>1)&3, jt = id>>3. 2 blocks/CU.
// Wave w streams k in [1024w, 1024w+1024) in 32-k steps.
// Per step: stage V(s+1) into private LDS dbuf (global_load_lds, no barrier — wave-private),
// prefetch K(s+1) to reg, counted s_waitcnt vmcnt(10) (= K(s)+8 stage(s+1)+K(s+1) in flight),
// ds_read V(s), then the split-pack 4-phase pipeline.
__global__ __launch_bounds__(256, 2) void attn_kernel(
        const unsigned short* __restrict__ qb, const unsigned short* __restrict__ kb,
        const unsigned short* __restrict__ vb, const float* __restrict__ x,
        const float* __restrict__ gamma_p, float* __restrict__ out) {
    // [0,65536): V stage dbuf = 2 bufs x 4 waves x 8KB. Epilogue obuf aliases [0,16896)
    // (safe: per-wave vmcnt(0) drain + __syncthreads before obuf is touched).
    // [65536,66560): lpart.
    __shared__ __align__(1024) char smem[66560];
    float (*lpart)[2][32] = (float (*)[2][32])(smem + 65536);
    float (*obuf)[32][33] = (float (*)[32][33])smem;

    int tid = threadIdx.x;
    int wv_ = __builtin_amdgcn_readfirstlane(tid >> 6);
    int lane = tid & 63;
    int l31 = lane & 31, lh = lane >> 5;
    int id = blockIdx.x;
    int cs = id & 1, b = (id >> 1) & 3, jt = id >> 3;
    int jbase = jt * 64, cb = cs * 128;
    int lane8 = lane * 8;
    int lane16 = lane * 16;

    char* st0 = smem + wv_ * 8192;       // buf0 wave base (uniform across wave)
    char* st1 = st0 + 32768;             // buf1

    const unsigned short* qfb = qb + ((size_t)b * 128 + (jbase >> 5)) * 512 + lane8;
    const unsigned short* kfb = kb + ((size_t)b * 128 + (wv_ * 32)) * 512 + lane8;

    short8 qf0 = *(const short8*)qfb;
    short8 qf1 = *(const short8*)(qfb + 512);

    floatx16 z16 = {0,0,0,0,0,0,0,0,0,0,0,0,0,0,0,0};
    floatx16 acc0[4], acc1[4];
#pragma unroll
    for (int cg = 0; cg < 4; ++cg) { acc0[cg] = z16; acc1[cg] = z16; }
    float lsum0 = 0.f, lsum1 = 0.f;

    const unsigned short* vp0 = vb + (((size_t)b * 8 + cs * 4 + 0) * 256 + wv_ * 64) * 512 + lane8;
    const unsigned short* vp1 = vb + (((size_t)b * 8 + cs * 4 + 1) * 256 + wv_ * 64) * 512 + lane8;
    const unsigned short* vp2 = vb + (((size_t)b * 8 + cs * 4 + 2) * 256 + wv_ * 64) * 512 + lane8;
    const unsigned short* vp3 = vb + (((size_t)b * 8 + cs * 4 + 3) * 256 + wv_ * 64) * 512 + lane8;

#define STAGE8(WRB) do { \
        gll16(vp0,       (WRB) + 0 * 1024); \
        gll16(vp1,       (WRB) + 1 * 1024); \
        gll16(vp2,       (WRB) + 2 * 1024); \
        gll16(vp3,       (WRB) + 3 * 1024); \
        gll16(vp0 + 512, (WRB) + 4 * 1024); \
        gll16(vp1 + 512, (WRB) + 5 * 1024); \
        gll16(vp2 + 512, (WRB) + 6 * 1024); \
        gll16(vp3 + 512, (WRB) + 7 * 1024); \
        vp0 += 1024; vp1 += 1024; vp2 += 1024; vp3 += 1024; \
    } while (0)

    // prologue: stage step 0, then K(0) (K load AFTER stage keeps the in-loop
    // vmcnt count uniform: newest-10 at each wait = {K(s), 8 stage(s+1), K(s+1)})
    STAGE8(st0);
    short8 ak0 = *(const short8*)kfb;
    short8 ak1;
    int kstep = 1;

#define STEP(RDB, WRB, AKC, AKN) do { \
        STAGE8(WRB); \
        AKN = *(const short8*)(kfb + (size_t)(kstep & 31) * 512); ++kstep; \
        __builtin_amdgcn_sched_barrier(0); \
        asm volatile("s_waitcnt vmcnt(10)" ::: "memory"); \
        __builtin_amdgcn_sched_barrier(0); \
        short8 vf0a = *(const short8*)((RDB) + 0 * 1024 + lane16); \
        short8 vf1a = *(const short8*)((RDB) + 1 * 1024 + lane16); \
        short8 vf2a = *(const short8*)((RDB) + 2 * 1024 + lane16); \
        short8 vf3a = *(const short8*)((RDB) + 3 * 1024 + lane16); \
        short8 vf0b = *(const short8*)((RDB) + 4 * 1024 + lane16); \
        short8 vf1b = *(const short8*)((RDB) + 5 * 1024 + lane16); \
        short8 vf2b = *(const short8*)((RDB) + 6 * 1024 + lane16); \
        short8 vf3b = *(const short8*)((RDB) + 7 * 1024 + lane16); \
        floatx16 sc0 = __builtin_amdgcn_mfma_f32_32x32x16_bf16(AKC, qf0, z16, 0, 0, 0); \
        floatx16 sc1 = __builtin_amdgcn_mfma_f32_32x32x16_bf16(AKC, qf1, z16, 0, 0, 0); \
        short8 A; \
        pack_half(sc0, 0, &A, &lsum0); \
        __builtin_amdgcn_s_setprio(1); \
        acc0[0] = __builtin_amdgcn_mfma_f32_32x32x16_bf16(A, vf0a, acc0[0], 0, 0, 0); \
        acc0[1] = __builtin_amdgcn_mfma_f32_32x32x16_bf16(A, vf1a, acc0[1], 0, 0, 0); \
        acc0[2] = __builtin_amdgcn_mfma_f32_32x32x16_bf16(A, vf2a, acc0[2], 0, 0, 0); \
        acc0[3] = __builtin_amdgcn_mfma_f32_32x32x16_bf16(A, vf3a, acc0[3], 0, 0, 0); \
        __builtin_amdgcn_s_setprio(0); \
        __builtin_amdgcn_sched_barrier(0); \
        pack_half(sc0, 1, &A, &lsum0); \
        __builtin_amdgcn_s_setprio(1); \
        acc0[0] = __builtin_amdgcn_mfma_f32_32x32x16_bf16(A, vf0b, acc0[0], 0, 0, 0); \
        acc0[1] = __builtin_amdgcn_mfma_f32_32x32x16_bf16(A, vf1b, acc0[1], 0, 0, 0); \
        acc0[2] = __builtin_amdgcn_mfma_f32_32x32x16_bf16(A, vf2b, acc0[2], 0, 0, 0); \
        acc0[3] = __builtin_amdgcn_mfma_f32_32x32x16_bf16(A, vf3b, acc0[3], 0, 0, 0); \
        __builtin_amdgcn_s_setprio(0); \
        __builtin_amdgcn_sched_barrier(0); \
        pack_half(sc1, 0, &A, &lsum1); \
        __builtin_amdgcn_s_setprio(1); \
        acc1[0] = __builtin_amdgcn_mfma_f32_32x32x16_bf16(A, vf0a, acc1[0], 0, 0, 0); \
        acc1[1] = __builtin_amdgcn_mfma_f32_32x32x16_bf16(A, vf1a, acc1[1], 0, 0, 0); \
        acc1[2] = __builtin_amdgcn_mfma_f32_32x32x16_bf16(A, vf2a, acc1[2], 0, 0, 0); \
        acc1[3] = __builtin_amdgcn_mfma_f32_32x32x16_bf16(A, vf3a, acc1[3], 0, 0, 0); \
        __builtin_amdgcn_s_setprio(0); \
        __builtin_amdgcn_sched_barrier(0); \
        pack_half(sc1, 1, &A, &lsum1); \
        __builtin_amdgcn_s_setprio(1); \
        acc1[0] = __builtin_amdgcn_mfma_f32_32x32x16_bf16(A, vf0b, acc1[0], 0, 0, 0); \
        acc1[1] = __builtin_amdgcn_mfma_f32_32x32x16_bf16(A, vf1b, acc1[1], 0, 0, 0); \
        acc1[2] = __builtin_amdgcn_mfma_f32_32x32x16_bf16(A, vf2b, acc1[2], 0, 0, 0); \
        acc1[3] = __builtin_amdgcn_mfma_f32_32x32x16_bf16(A, vf3b, acc1[3], 0, 0, 0); \
        __builtin_amdgcn_s_setprio(0); \
    } while (0)

#pragma unroll 1
    for (int it = 0; it < 16; ++it) {
        STEP(st0, st1, ak0, ak1);
        STEP(st1, st0, ak1, ak0);
    }
#undef STEP
#undef STAGE8

    // Drain in-flight global_load_lds before smem is reused as obuf (per-wave
    // drain; the following __syncthreads makes it block-wide).
    __builtin_amdgcn_sched_barrier(0);
    asm volatile("s_waitcnt vmcnt(0)" ::: "memory");
    __builtin_amdgcn_sched_barrier(0);

    lsum0 += __shfl_xor(lsum0, 32, 64);
    lsum1 += __shfl_xor(lsum1, 32, 64);
    if (lh == 0) { lpart[wv_][0][l31] = lsum0; lpart[wv_][1][l31] = lsum1; }
    __syncthreads();

    int j31 = tid & 31;
    float gamma = gamma_p[0];
    float gl0 = gamma / (lpart[0][0][j31] + lpart[1][0][j31] + lpart[2][0][j31] + lpart[3][0][j31]);
    float gl1 = gamma / (lpart[0][1][j31] + lpart[1][1][j31] + lpart[2][1][j31] + lpart[3][1][j31]);
    const float* xbb = x + (size_t)b * CC * NN;
    float* obb = out + (size_t)b * CC * NN;
    int hofs = lh * 4;
    int cgrp = tid >> 5;
#pragma unroll
    for (int jg = 0; jg < 2; ++jg) {
        float gl = jg ? gl1 : gl0;
#pragma unroll
        for (int cg = 0; cg < 4; ++cg) {
            __syncthreads();
            const floatx16& a = jg ? acc1[cg] : acc0[cg];
#pragma unroll
            for (int r = 0; r < 16; ++r) {
                int row = (r & 3) + 8 * (r >> 2) + hofs;
                obuf[wv_][row][l31] = a[r];
            }
            __syncthreads();
#pragma unroll
            for (int i = 0; i < 4; ++i) {
                int c = cgrp * 4 + i;
                float val = obuf[0][j31][c] + obuf[1][j31][c] + obuf[2][j31][c] + obuf[3][j31][c];
                size_t oidx = (size_t)(cb + cg * 32 + c) * NN + jbase + jg * 32 + j31;
                obb[oidx] = fmaf(gl, val, xbb[oidx]);
            }
        }
    }
}

extern "C" void kernel_launch(void* const* d_in, const int* in_sizes, int n_in,
                              void* d_out, int out_size, void* d_ws, size_t ws_size,
                              hipStream_t stream) {
    const float* x     = (const float*)d_in[0];
    const float* wq    = (const float*)d_in[1];
    const float* bq    = (const float*)d_in[2];
    const float* wk    = (const float*)d_in[3];
    const float* bk    = (const float*)d_in[4];
    const float* wv    = (const float*)d_in[5];
    const float* bv    = (const float*)d_in[6];
    const float* gamma = (const float*)d_in[7];
    const float* eps_q = (const float*)d_in[8];
    const float* eps_k = (const float*)d_in[9];
    float* out = (float*)d_out;

    char* ws = (char*)d_ws;
    unsigned short* qrawh = (unsigned short*)ws;                     // 512 KB (1 MB slot)
    unsigned short* krawh = (unsigned short*)(ws + (1u << 20));      // 512 KB (1 MB slot)
    float* nu2  = (float*)(ws + (2u << 20));                         // 512 B
    unsigned short* qb = (unsigned short*)(ws + (2u << 20) + 4096);  // 512 KB
    unsigned short* kb = qb + (size_t)NB * NN * C16;                 // 512 KB
    unsigned short* vb = kb + (size_t)NB * NN * C16;                 // 8 MB
    unsigned short* xT = vb + (size_t)NB * CC * NN;                  // 8 MB
    unsigned short* wvb = xT + (size_t)NB * NN * CC;                 // 128 KB
    unsigned short* wqkb = wvb + (size_t)CC * CC;                    // 48 KB

    prep_kernel<<<dim3(1112), dim3(256), 0, stream>>>(x, wv, wq, wk, xT, wvb, wqkb, nu2);
    conv_kernel<<<dim3(768), dim3(256), 0, stream>>>(xT, wvb, wqkb, bv, bq, bk, vb, qrawh, krawh, nu2);
    frn_mish_kernel<<<dim3(512), dim3(256), 0, stream>>>(qrawh, krawh, nu2, eps_q, eps_k, qb, kb);
    attn_kernel<<<dim3(512), dim3(256), 0, stream>>>(qb, kb, vb, x, gamma, out);
}

// Round 6
// 163.364 us; speedup vs baseline: 1.0177x; 1.0177x over previous
//
#include <hip/hip_runtime.h>
#include <stdint.h>

#define NB 4
#define CC 256
#define C16 16
#define HH 64
#define WW 64
#define NN 4096

typedef __attribute__((ext_vector_type(8))) short short8;
typedef __attribute__((ext_vector_type(4))) float floatx4;
typedef __attribute__((ext_vector_type(16))) float floatx16;

#if __has_builtin(__builtin_amdgcn_exp2f)
#define EXP2(x) __builtin_amdgcn_exp2f(x)
#else
#define EXP2(x) exp2f(x)
#endif

__device__ __forceinline__ unsigned short f2bf(float f) {
    union { float f; unsigned u; } v; v.f = f;
    unsigned r = v.u + 0x7fffu + ((v.u >> 16) & 1u);
    return (unsigned short)(r >> 16);
}
__device__ __forceinline__ float bf2f(unsigned short h) {
    union { unsigned u; float f; } v; v.u = (unsigned)h << 16;
    return v.f;
}

// Fragment-major layouts (frag = 32 rows x 16 k = 64 lanes x 8 bf16 = 1KB):
//   qb/kb: frag f = b*128 + (n>>5); addr = f*512 + (n&31 + 32*(o>>3))*8 + (o&7)
//   vb:    frag f = (b*8 + (c>>5))*256 + (n>>4); addr = f*512 + (c&31 + 32*((n>>3)&1))*8 + (n&7)

// ========== K1: cast x->xT bf16 [b][n][c] (vectorized); cast wv/wq/wk; zero nu2 ==========
__global__ __launch_bounds__(256) void prep_kernel(
        const float* __restrict__ x, const float* __restrict__ wv,
        const float* __restrict__ wq, const float* __restrict__ wk,
        unsigned short* __restrict__ xT, unsigned short* __restrict__ wvb,
        unsigned short* __restrict__ wqkb, float* __restrict__ nu2) {
    int bid = blockIdx.x;
    if (bid < 1024) {
        __shared__ float tile_t[64][65];   // [n-local][c-local], pad 65: 2-way free
        int nt = bid & 63, ct = (bid >> 6) & 3, b = bid >> 8;
        int n0 = nt * 64, c0 = ct * 64;
        int tid = threadIdx.x;
        int rg = tid >> 4, f = tid & 15;
        const float* xb = x + ((size_t)b * CC + c0) * NN + n0;
#pragma unroll
        for (int p = 0; p < 4; ++p) {
            int c = p * 16 + rg;
            float4 v = *(const float4*)(xb + (size_t)c * NN + f * 4);
            tile_t[f * 4 + 0][c] = v.x;
            tile_t[f * 4 + 1][c] = v.y;
            tile_t[f * 4 + 2][c] = v.z;
            tile_t[f * 4 + 3][c] = v.w;
        }
        __syncthreads();
        unsigned short* xtb = xT + ((size_t)b * NN + n0) * CC + c0;
#pragma unroll
        for (int p = 0; p < 4; ++p) {
            int n = p * 16 + rg;
            ushort4 st;
            st.x = f2bf(tile_t[n][f * 4 + 0]);
            st.y = f2bf(tile_t[n][f * 4 + 1]);
            st.z = f2bf(tile_t[n][f * 4 + 2]);
            st.w = f2bf(tile_t[n][f * 4 + 3]);
            *(ushort4*)(xtb + (size_t)n * CC + f * 4) = st;
        }
    } else {
        int idx = (bid - 1024) * 256 + threadIdx.x;
        if (bid == 1024 && threadIdx.x < 128) nu2[threadIdx.x] = 0.f;
        if (idx < 16384) {
            float4 v = *(const float4*)(wv + idx * 4);
            ushort4 o;
            o.x = f2bf(v.x); o.y = f2bf(v.y); o.z = f2bf(v.z); o.w = f2bf(v.w);
            *(ushort4*)(wvb + idx * 4) = o;
        } else if (idx < 16384 + 6144) {
            int base = (idx - 16384) * 4;
#pragma unroll
            for (int u = 0; u < 4; ++u) {
                int e = base + u;
                int t = e / 12288;
                int i = e - t * 12288;
                int tap = i >> 12, o = (i >> 8) & 15, c = i & 255;
                const float* src = t ? wk : wq;
                wqkb[e] = f2bf(src[o * 768 + c * 3 + tap]);
            }
        }
    }
}

// ========== K2: conv_v (0..511) + conv_qk w/ FRN-ssq atomics (512..767) ==========
__global__ __launch_bounds__(256) void conv_kernel(
        const unsigned short* __restrict__ xT, const unsigned short* __restrict__ wvb,
        const unsigned short* __restrict__ wqkb, const float* __restrict__ bv,
        const float* __restrict__ bq, const float* __restrict__ bk,
        unsigned short* __restrict__ vb, unsigned short* __restrict__ qrawh,
        unsigned short* __restrict__ krawh, float* __restrict__ nu2) {
    int bid = blockIdx.x;
    int tid = threadIdx.x;
    int wv_ = tid >> 6, lane = tid & 63;
    int q16 = lane >> 4, c16 = lane & 15;
    if (bid < 512) {
        int ntile = bid & 63, b = (bid >> 6) & 3, ch = bid >> 8;
        int n0 = ntile * 64;
        int cb = ch * 128 + wv_ * 32;
        floatx4 fzero = {0.f, 0.f, 0.f, 0.f};
        floatx4 acc[2][4];
        for (int ct = 0; ct < 2; ++ct)
            for (int nt = 0; nt < 4; ++nt) acc[ct][nt] = fzero;
        const unsigned short* xb = xT + ((size_t)b * NN + n0) * CC;
        for (int kc = 0; kc < 8; ++kc) {
            int ko = kc * 32 + q16 * 8;
            short8 a0 = *(const short8*)(wvb + (size_t)(cb + c16) * CC + ko);
            short8 a1 = *(const short8*)(wvb + (size_t)(cb + 16 + c16) * CC + ko);
            short8 bf[4];
#pragma unroll
            for (int nt = 0; nt < 4; ++nt)
                bf[nt] = *(const short8*)(xb + (size_t)(nt * 16 + c16) * CC + ko);
#pragma unroll
            for (int nt = 0; nt < 4; ++nt) {
                acc[0][nt] = __builtin_amdgcn_mfma_f32_16x16x32_bf16(bf[nt], a0, acc[0][nt], 0, 0, 0);
                acc[1][nt] = __builtin_amdgcn_mfma_f32_16x16x32_bf16(bf[nt], a1, acc[1][nt], 0, 0, 0);
            }
        }
        // C: row = q16*4+r -> n-local, col = c16 -> c-local. ushort4 frag-major stores.
        float bv0 = bv[cb + c16], bv1 = bv[cb + 16 + c16];
        int off = 32 * 8 * (q16 >> 1) + (q16 & 1) * 4 + c16 * 8;
#pragma unroll
        for (int ct = 0; ct < 2; ++ct) {
            float bvv = ct ? bv1 : bv0;
#pragma unroll
            for (int nt = 0; nt < 4; ++nt) {
                size_t fb = (((size_t)b * 8 + ch * 4 + wv_) * 256 + (n0 >> 4) + nt) * 512;
                ushort4 st;
                st.x = f2bf(acc[ct][nt][0] + bvv);
                st.y = f2bf(acc[ct][nt][1] + bvv);
                st.z = f2bf(acc[ct][nt][2] + bvv);
                st.w = f2bf(acc[ct][nt][3] + bvv);
                *(ushort4*)(vb + fb + off + ct * 16 * 8) = st;
            }
        }
    } else {
        int cv = bid - 512;
        int nb2 = cv & 63, b = cv >> 6;
        int nl = nb2 * 64 + wv_ * 16 + c16;     // load-n (A-frag m index)
        int h = nl >> 6, w = nl & 63;
        bool vm1 = (w != 0), vp1 = (w != 63);
        bool vm64 = (h != 0), vp64 = (h != 63);
        short8 zero8 = {0, 0, 0, 0, 0, 0, 0, 0};
        floatx4 accq = {0.f, 0.f, 0.f, 0.f}, acck = {0.f, 0.f, 0.f, 0.f};
        const unsigned short* xb = xT + (size_t)b * NN * CC;
        const unsigned short* wrow = wqkb + c16 * 256;
        for (int kc = 0; kc < 8; ++kc) {
            int ko = kc * 32 + q16 * 8;
            short8 b0 = *(const short8*)(xb + (size_t)nl * CC + ko);
            short8 bm1 = vm1 ? *(const short8*)(xb + (size_t)(nl - 1) * CC + ko) : zero8;
            short8 bp1 = vp1 ? *(const short8*)(xb + (size_t)(nl + 1) * CC + ko) : zero8;
            short8 bm64 = vm64 ? *(const short8*)(xb + (size_t)(nl - 64) * CC + ko) : zero8;
            short8 bp64 = vp64 ? *(const short8*)(xb + (size_t)(nl + 64) * CC + ko) : zero8;
            short8 aq0 = *(const short8*)(wrow + 0 * 4096 + ko);
            short8 aq1 = *(const short8*)(wrow + 1 * 4096 + ko);
            short8 aq2 = *(const short8*)(wrow + 2 * 4096 + ko);
            short8 ak0 = *(const short8*)(wrow + 12288 + 0 * 4096 + ko);
            short8 ak1 = *(const short8*)(wrow + 12288 + 1 * 4096 + ko);
            short8 ak2 = *(const short8*)(wrow + 12288 + 2 * 4096 + ko);
            accq = __builtin_amdgcn_mfma_f32_16x16x32_bf16(bm1, aq0, accq, 0, 0, 0);
            accq = __builtin_amdgcn_mfma_f32_16x16x32_bf16(b0, aq1, accq, 0, 0, 0);
            accq = __builtin_amdgcn_mfma_f32_16x16x32_bf16(bp1, aq2, accq, 0, 0, 0);
            acck = __builtin_amdgcn_mfma_f32_16x16x32_bf16(bm64, ak0, acck, 0, 0, 0);
            acck = __builtin_amdgcn_mfma_f32_16x16x32_bf16(b0, ak1, acck, 0, 0, 0);
            acck = __builtin_amdgcn_mfma_f32_16x16x32_bf16(bp64, ak2, acck, 0, 0, 0);
        }
        // C: row = q16*4+r -> n, col = c16 -> o. bf16 ushort4 stores.
        int nst = nb2 * 64 + wv_ * 16 + q16 * 4;
        float bqv = bq[c16], bkv = bk[c16];
        ushort4 sq4, sk4;
        float ssq = 0.f, ssk = 0.f;
        {
            float vq0 = accq[0] + bqv, vq1 = accq[1] + bqv, vq2 = accq[2] + bqv, vq3 = accq[3] + bqv;
            float vk0 = acck[0] + bkv, vk1 = acck[1] + bkv, vk2 = acck[2] + bkv, vk3 = acck[3] + bkv;
            sq4.x = f2bf(vq0); sq4.y = f2bf(vq1); sq4.z = f2bf(vq2); sq4.w = f2bf(vq3);
            sk4.x = f2bf(vk0); sk4.y = f2bf(vk1); sk4.z = f2bf(vk2); sk4.w = f2bf(vk3);
            ssq = vq0 * vq0 + vq1 * vq1 + vq2 * vq2 + vq3 * vq3;
            ssk = vk0 * vk0 + vk1 * vk1 + vk2 * vk2 + vk3 * vk3;
        }
        *(ushort4*)(qrawh + (size_t)(b * C16 + c16) * NN + nst) = sq4;
        *(ushort4*)(krawh + (size_t)(b * C16 + c16) * NN + nst) = sk4;
        ssq += __shfl_xor(ssq, 16, 64);
        ssq += __shfl_xor(ssq, 32, 64);
        ssk += __shfl_xor(ssk, 16, 64);
        ssk += __shfl_xor(ssk, 32, 64);
        if (lane < 16) {
            atomicAdd(nu2 + b * C16 + lane, ssq);
            atomicAdd(nu2 + 64 + b * C16 + lane, ssk);
        }
    }
}

// ========== K3: FRN + Mish (bf16 input), frag-major out; 512 blocks, 4 ch/thread ==========
// q additionally scaled by log2(e) so attention can use exp2.
// Mish via algebraic identity: e^{softplus(v)} = 1+e^v, so
// tanh(softplus(v)) = ((1+t)^2-1)/((1+t)^2+1) = (t^2+2t)/(t^2+2t+2), t=e^v.
// One hw exp2 + FMAs + rcp replaces expf+log1pf+tanhf. Guard v>30 (tanh==1 to 2e-26).
__global__ __launch_bounds__(256) void frn_mish_kernel(
        const unsigned short* __restrict__ qrawh, const unsigned short* __restrict__ krawh,
        const float* __restrict__ nu2, const float* __restrict__ eps_q,
        const float* __restrict__ eps_k, unsigned short* __restrict__ qb,
        unsigned short* __restrict__ kb) {
    int blk = blockIdx.x;                 // 512 = tensor(2) x b(4) x nchunk(64)
    int tensor = blk >> 8;
    int b = (blk >> 6) & 3;
    int nch = blk & 63;
    const unsigned short* raw = tensor ? krawh : qrawh;
    const float* eps = tensor ? eps_k : eps_q;
    unsigned short* outp = tensor ? kb : qb;
    const float* nu = nu2 + tensor * 64 + b * C16;
    float scale = tensor ? 1.0f : 1.44269504f;
    int n = nch * 64 + (threadIdx.x & 63);
    int oq = threadIdx.x >> 6;            // 0..3 -> channels oq*4..oq*4+3
    ushort4 pk4;
#pragma unroll
    for (int i = 0; i < 4; ++i) {
        int o = oq * 4 + i;
        float r = bf2f(raw[(size_t)(b * C16 + o) * NN + n]);
        float v = r * rsqrtf(nu[o] * (1.f / (float)NN) + fabsf(eps[o]));
        float t = EXP2(v * 1.44269504f);
        float num = t * t + 2.0f * t;
        float m = (v * num) * __builtin_amdgcn_rcpf(num + 2.0f);
        if (v > 30.f) m = v;
        m *= scale;
        ((unsigned short*)&pk4)[i] = f2bf(m);
    }
    size_t base = ((size_t)b * 128 + (n >> 5)) * 512 + (size_t)(n & 31) * 8
                + (size_t)(oq >> 1) * 256 + (oq & 1) * 4;
    *(ushort4*)(outp + base) = pk4;
}

// exp2 (NO shift — softmax is shift-invariant; S range fits f32/bf16 exponent span).
// Half-pack: 8 score elements (half of a floatx16) -> one bf16 A-frag word via
// v_permlane32_swap_b32. h must be a literal (inlined). Numerically identical to
// the old pack_p0 (same ops, same order per element).
__device__ __forceinline__ void pack_half(
        const floatx16& sc, int h, short8* A, float* lsum) {
    unsigned pk[4];
    float ls = 0.f;
#pragma unroll
    for (int p = 0; p < 4; ++p) {
        float e0 = EXP2(sc[8 * h + 2 * p]);
        float e1 = EXP2(sc[8 * h + 2 * p + 1]);
        ls += e0 + e1;
        pk[p] = __builtin_amdgcn_perm(__float_as_uint(e1), __float_as_uint(e0), 0x07060302u);
    }
    *lsum += ls;
    asm("v_permlane32_swap_b32 %0, %1" : "+v"(pk[0]), "+v"(pk[2]));
    asm("v_permlane32_swap_b32 %0, %1" : "+v"(pk[1]), "+v"(pk[3]));
    union { unsigned u[4]; short8 s; } a;
    a.u[0] = pk[0]; a.u[1] = pk[1]; a.u[2] = pk[2]; a.u[3] = pk[3];
    *A = a.s;
}

// ========== K4: attention, j=64 c=128 per block, split-pack interleaved ==========
// (reverted to round-3 structure — best measured: 49.6 us)
// grid 512: cs = id&1 (128-c), b = (id>>1)&3, jt = id>>3. 2 blocks/CU.
// Wave w streams k in [1024w, 1024w+1024) in 32-k steps.
// Per step, four {pack-half -> 4 PV MFMA} phases; sched_barrier(0) pins the
// interleave so each pack-half's VALU issues under the previous MFMA group.
__global__ __launch_bounds__(256, 2) void attn_kernel(
        const unsigned short* __restrict__ qb, const unsigned short* __restrict__ kb,
        const unsigned short* __restrict__ vb, const float* __restrict__ x,
        const float* __restrict__ gamma_p, float* __restrict__ out) {
    __shared__ float lpart[4][2][32];
    __shared__ float obuf[4][32][33];

    int tid = threadIdx.x;
    int wv_ = __builtin_amdgcn_readfirstlane(tid >> 6);
    int lane = tid & 63;
    int l31 = lane & 31, lh = lane >> 5;
    int id = blockIdx.x;
    int cs = id & 1, b = (id >> 1) & 3, jt = id >> 3;
    int jbase = jt * 64, cb = cs * 128;
    int lane8 = lane * 8;

    const unsigned short* qfb = qb + ((size_t)b * 128 + (jbase >> 5)) * 512 + lane8;
    const unsigned short* kfb = kb + ((size_t)b * 128 + (wv_ * 32)) * 512 + lane8;

    short8 qf0 = *(const short8*)qfb;
    short8 qf1 = *(const short8*)(qfb + 512);

    floatx16 z16 = {0,0,0,0,0,0,0,0,0,0,0,0,0,0,0,0};
    floatx16 acc0[4], acc1[4];
#pragma unroll
    for (int cg = 0; cg < 4; ++cg) { acc0[cg] = z16; acc1[cg] = z16; }
    float lsum0 = 0.f, lsum1 = 0.f;

    const unsigned short* vp0 = vb + (((size_t)b * 8 + cs * 4 + 0) * 256 + wv_ * 64) * 512 + lane8;
    const unsigned short* vp1 = vb + (((size_t)b * 8 + cs * 4 + 1) * 256 + wv_ * 64) * 512 + lane8;
    const unsigned short* vp2 = vb + (((size_t)b * 8 + cs * 4 + 2) * 256 + wv_ * 64) * 512 + lane8;
    const unsigned short* vp3 = vb + (((size_t)b * 8 + cs * 4 + 3) * 256 + wv_ * 64) * 512 + lane8;

    short8 ak = *(const short8*)kfb;
#pragma unroll 1
    for (int step = 0; step < 32; ++step) {
        // a-fragments first, b-fragments second: first PV group waits only vmcnt(4)
        short8 vf0a = *(const short8*)vp0;
        short8 vf1a = *(const short8*)vp1;
        short8 vf2a = *(const short8*)vp2;
        short8 vf3a = *(const short8*)vp3;
        short8 vf0b = *(const short8*)(vp0 + 512);
        short8 vf1b = *(const short8*)(vp1 + 512);
        short8 vf2b = *(const short8*)(vp2 + 512);
        short8 vf3b = *(const short8*)(vp3 + 512);
        floatx16 sc0 = __builtin_amdgcn_mfma_f32_32x32x16_bf16(ak, qf0, z16, 0, 0, 0);
        floatx16 sc1 = __builtin_amdgcn_mfma_f32_32x32x16_bf16(ak, qf1, z16, 0, 0, 0);
        ak = *(const short8*)(kfb + (size_t)((step + 1) & 31) * 512);
        short8 A;
        pack_half(sc0, 0, &A, &lsum0);                 // A00
        __builtin_amdgcn_s_setprio(1);
        acc0[0] = __builtin_amdgcn_mfma_f32_32x32x16_bf16(A, vf0a, acc0[0], 0, 0, 0);
        acc0[1] = __builtin_amdgcn_mfma_f32_32x32x16_bf16(A, vf1a, acc0[1], 0, 0, 0);
        acc0[2] = __builtin_amdgcn_mfma_f32_32x32x16_bf16(A, vf2a, acc0[2], 0, 0, 0);
        acc0[3] = __builtin_amdgcn_mfma_f32_32x32x16_bf16(A, vf3a, acc0[3], 0, 0, 0);
        __builtin_amdgcn_s_setprio(0);
        __builtin_amdgcn_sched_barrier(0);
        pack_half(sc0, 1, &A, &lsum0);                 // A01
        __builtin_amdgcn_s_setprio(1);
        acc0[0] = __builtin_amdgcn_mfma_f32_32x32x16_bf16(A, vf0b, acc0[0], 0, 0, 0);
        acc0[1] = __builtin_amdgcn_mfma_f32_32x32x16_bf16(A, vf1b, acc0[1], 0, 0, 0);
        acc0[2] = __builtin_amdgcn_mfma_f32_32x32x16_bf16(A, vf2b, acc0[2], 0, 0, 0);
        acc0[3] = __builtin_amdgcn_mfma_f32_32x32x16_bf16(A, vf3b, acc0[3], 0, 0, 0);
        __builtin_amdgcn_s_setprio(0);
        __builtin_amdgcn_sched_barrier(0);
        pack_half(sc1, 0, &A, &lsum1);                 // A10
        __builtin_amdgcn_s_setprio(1);
        acc1[0] = __builtin_amdgcn_mfma_f32_32x32x16_bf16(A, vf0a, acc1[0], 0, 0, 0);
        acc1[1] = __builtin_amdgcn_mfma_f32_32x32x16_bf16(A, vf1a, acc1[1], 0, 0, 0);
        acc1[2] = __builtin_amdgcn_mfma_f32_32x32x16_bf16(A, vf2a, acc1[2], 0, 0, 0);
        acc1[3] = __builtin_amdgcn_mfma_f32_32x32x16_bf16(A, vf3a, acc1[3], 0, 0, 0);
        __builtin_amdgcn_s_setprio(0);
        __builtin_amdgcn_sched_barrier(0);
        pack_half(sc1, 1, &A, &lsum1);                 // A11
        __builtin_amdgcn_s_setprio(1);
        acc1[0] = __builtin_amdgcn_mfma_f32_32x32x16_bf16(A, vf0b, acc1[0], 0, 0, 0);
        acc1[1] = __builtin_amdgcn_mfma_f32_32x32x16_bf16(A, vf1b, acc1[1], 0, 0, 0);
        acc1[2] = __builtin_amdgcn_mfma_f32_32x32x16_bf16(A, vf2b, acc1[2], 0, 0, 0);
        acc1[3] = __builtin_amdgcn_mfma_f32_32x32x16_bf16(A, vf3b, acc1[3], 0, 0, 0);
        __builtin_amdgcn_s_setprio(0);
        vp0 += 1024; vp1 += 1024; vp2 += 1024; vp3 += 1024;
    }

    lsum0 += __shfl_xor(lsum0, 32, 64);
    lsum1 += __shfl_xor(lsum1, 32, 64);
    if (lh == 0) { lpart[wv_][0][l31] = lsum0; lpart[wv_][1][l31] = lsum1; }
    __syncthreads();

    int j31 = tid & 31;
    float gamma = gamma_p[0];
    float gl0 = gamma / (lpart[0][0][j31] + lpart[1][0][j31] + lpart[2][0][j31] + lpart[3][0][j31]);
    float gl1 = gamma / (lpart[0][1][j31] + lpart[1][1][j31] + lpart[2][1][j31] + lpart[3][1][j31]);
    const float* xbb = x + (size_t)b * CC * NN;
    float* obb = out + (size_t)b * CC * NN;
    int hofs = lh * 4;
    int cgrp = tid >> 5;
#pragma unroll
    for (int jg = 0; jg < 2; ++jg) {
        float gl = jg ? gl1 : gl0;
#pragma unroll
        for (int cg = 0; cg < 4; ++cg) {
            __syncthreads();
            const floatx16& a = jg ? acc1[cg] : acc0[cg];
#pragma unroll
            for (int r = 0; r < 16; ++r) {
                int row = (r & 3) + 8 * (r >> 2) + hofs;
                obuf[wv_][row][l31] = a[r];
            }
            __syncthreads();
#pragma unroll
            for (int i = 0; i < 4; ++i) {
                int c = cgrp * 4 + i;
                float val = obuf[0][j31][c] + obuf[1][j31][c] + obuf[2][j31][c] + obuf[3][j31][c];
                size_t oidx = (size_t)(cb + cg * 32 + c) * NN + jbase + jg * 32 + j31;
                obb[oidx] = fmaf(gl, val, xbb[oidx]);
            }
        }
    }
}

extern "C" void kernel_launch(void* const* d_in, const int* in_sizes, int n_in,
                              void* d_out, int out_size, void* d_ws, size_t ws_size,
                              hipStream_t stream) {
    const float* x     = (const float*)d_in[0];
    const float* wq    = (const float*)d_in[1];
    const float* bq    = (const float*)d_in[2];
    const float* wk    = (const float*)d_in[3];
    const float* bk    = (const float*)d_in[4];
    const float* wv    = (const float*)d_in[5];
    const float* bv    = (const float*)d_in[6];
    const float* gamma = (const float*)d_in[7];
    const float* eps_q = (const float*)d_in[8];
    const float* eps_k = (const float*)d_in[9];
    float* out = (float*)d_out;

    char* ws = (char*)d_ws;
    unsigned short* qrawh = (unsigned short*)ws;                     // 512 KB (1 MB slot)
    unsigned short* krawh = (unsigned short*)(ws + (1u << 20));      // 512 KB (1 MB slot)
    float* nu2  = (float*)(ws + (2u << 20));                         // 512 B
    unsigned short* qb = (unsigned short*)(ws + (2u << 20) + 4096);  // 512 KB
    unsigned short* kb = qb + (size_t)NB * NN * C16;                 // 512 KB
    unsigned short* vb = kb + (size_t)NB * NN * C16;                 // 8 MB
    unsigned short* xT = vb + (size_t)NB * CC * NN;                  // 8 MB
    unsigned short* wvb = xT + (size_t)NB * NN * CC;                 // 128 KB
    unsigned short* wqkb = wvb + (size_t)CC * CC;                    // 48 KB

    prep_kernel<<<dim3(1112), dim3(256), 0, stream>>>(x, wv, wq, wk, xT, wvb, wqkb, nu2);
    conv_kernel<<<dim3(768), dim3(256), 0, stream>>>(xT, wvb, wqkb, bv, bq, bk, vb, qrawh, krawh, nu2);
    frn_mish_kernel<<<dim3(512), dim3(256), 0, stream>>>(qrawh, krawh, nu2, eps_q, eps_k, qb, kb);
    attn_kernel<<<dim3(512), dim3(256), 0, stream>>>(qb, kb, vb, x, gamma, out);
}

// Round 7
// 162.901 us; speedup vs baseline: 1.0206x; 1.0028x over previous
//
#include <hip/hip_runtime.h>
#include <hip/hip_cooperative_groups.h>
#include <stdint.h>

namespace cg = cooperative_groups;

#define NB 4
#define CC 256
#define C16 16
#define HH 64
#define WW 64
#define NN 4096

typedef __attribute__((ext_vector_type(8))) short short8;
typedef __attribute__((ext_vector_type(4))) float floatx4;
typedef __attribute__((ext_vector_type(16))) float floatx16;

#if __has_builtin(__builtin_amdgcn_exp2f)
#define EXP2(x) __builtin_amdgcn_exp2f(x)
#else
#define EXP2(x) exp2f(x)
#endif

__device__ __forceinline__ unsigned short f2bf(float f) {
    union { float f; unsigned u; } v; v.f = f;
    unsigned r = v.u + 0x7fffu + ((v.u >> 16) & 1u);
    return (unsigned short)(r >> 16);
}
__device__ __forceinline__ float bf2f(unsigned short h) {
    union { unsigned u; float f; } v; v.u = (unsigned)h << 16;
    return v.f;
}

// Fragment-major layouts (frag = 32 rows x 16 k = 64 lanes x 8 bf16 = 1KB):
//   qb/kb: frag f = b*128 + (n>>5); addr = f*512 + (n&31 + 32*(o>>3))*8 + (o&7)
//   vb:    frag f = (b*8 + (c>>5))*256 + (n>>4); addr = f*512 + (c&31 + 32*((n>>3)&1))*8 + (n&7)

// ================= phase bodies (shared by mega kernel and fallback kernels) ==========

__device__ __forceinline__ void prep_tile_body(
        int vb, const float* __restrict__ x, unsigned short* __restrict__ xT,
        float (*tile_t)[65], int tid) {
    // [n-local][c-local], pad 65: 2-way free
    int nt = vb & 63, ct = (vb >> 6) & 3, b = vb >> 8;
    int n0 = nt * 64, c0 = ct * 64;
    int rg = tid >> 4, f = tid & 15;
    const float* xb = x + ((size_t)b * CC + c0) * NN + n0;
#pragma unroll
    for (int p = 0; p < 4; ++p) {
        int c = p * 16 + rg;
        float4 v = *(const float4*)(xb + (size_t)c * NN + f * 4);
        tile_t[f * 4 + 0][c] = v.x;
        tile_t[f * 4 + 1][c] = v.y;
        tile_t[f * 4 + 2][c] = v.z;
        tile_t[f * 4 + 3][c] = v.w;
    }
    __syncthreads();
    unsigned short* xtb = xT + ((size_t)b * NN + n0) * CC + c0;
#pragma unroll
    for (int p = 0; p < 4; ++p) {
        int n = p * 16 + rg;
        ushort4 st;
        st.x = f2bf(tile_t[n][f * 4 + 0]);
        st.y = f2bf(tile_t[n][f * 4 + 1]);
        st.z = f2bf(tile_t[n][f * 4 + 2]);
        st.w = f2bf(tile_t[n][f * 4 + 3]);
        *(ushort4*)(xtb + (size_t)n * CC + f * 4) = st;
    }
}

__device__ __forceinline__ void prep_wt_body(
        int vb, const float* __restrict__ wv, const float* __restrict__ wq,
        const float* __restrict__ wk, unsigned short* __restrict__ wvb,
        unsigned short* __restrict__ wqkb, float* __restrict__ nu2, int tid) {
    int idx = (vb - 1024) * 256 + tid;
    if (vb == 1024 && tid < 128) nu2[tid] = 0.f;
    if (idx < 16384) {
        float4 v = *(const float4*)(wv + idx * 4);
        ushort4 o;
        o.x = f2bf(v.x); o.y = f2bf(v.y); o.z = f2bf(v.z); o.w = f2bf(v.w);
        *(ushort4*)(wvb + idx * 4) = o;
    } else if (idx < 16384 + 6144) {
        int base = (idx - 16384) * 4;
#pragma unroll
        for (int u = 0; u < 4; ++u) {
            int e = base + u;
            int t = e / 12288;
            int i = e - t * 12288;
            int tap = i >> 12, o = (i >> 8) & 15, c = i & 255;
            const float* src = t ? wk : wq;
            wqkb[e] = f2bf(src[o * 768 + c * 3 + tap]);
        }
    }
}

__device__ __forceinline__ void conv_v_body(
        int vb, const unsigned short* __restrict__ xT, const unsigned short* __restrict__ wvb,
        const float* __restrict__ bv, unsigned short* __restrict__ vbuf, int tid) {
    int wv_ = tid >> 6, lane = tid & 63;
    int q16 = lane >> 4, c16 = lane & 15;
    int ntile = vb & 63, b = (vb >> 6) & 3, ch = vb >> 8;
    int n0 = ntile * 64;
    int cb = ch * 128 + wv_ * 32;
    floatx4 fzero = {0.f, 0.f, 0.f, 0.f};
    floatx4 acc[2][4];
    for (int ct = 0; ct < 2; ++ct)
        for (int nt = 0; nt < 4; ++nt) acc[ct][nt] = fzero;
    const unsigned short* xb = xT + ((size_t)b * NN + n0) * CC;
    for (int kc = 0; kc < 8; ++kc) {
        int ko = kc * 32 + q16 * 8;
        short8 a0 = *(const short8*)(wvb + (size_t)(cb + c16) * CC + ko);
        short8 a1 = *(const short8*)(wvb + (size_t)(cb + 16 + c16) * CC + ko);
        short8 bf[4];
#pragma unroll
        for (int nt = 0; nt < 4; ++nt)
            bf[nt] = *(const short8*)(xb + (size_t)(nt * 16 + c16) * CC + ko);
#pragma unroll
        for (int nt = 0; nt < 4; ++nt) {
            acc[0][nt] = __builtin_amdgcn_mfma_f32_16x16x32_bf16(bf[nt], a0, acc[0][nt], 0, 0, 0);
            acc[1][nt] = __builtin_amdgcn_mfma_f32_16x16x32_bf16(bf[nt], a1, acc[1][nt], 0, 0, 0);
        }
    }
    // C: row = q16*4+r -> n-local, col = c16 -> c-local. ushort4 frag-major stores.
    float bv0 = bv[cb + c16], bv1 = bv[cb + 16 + c16];
    int off = 32 * 8 * (q16 >> 1) + (q16 & 1) * 4 + c16 * 8;
#pragma unroll
    for (int ct = 0; ct < 2; ++ct) {
        float bvv = ct ? bv1 : bv0;
#pragma unroll
        for (int nt = 0; nt < 4; ++nt) {
            size_t fb = (((size_t)b * 8 + ch * 4 + wv_) * 256 + (n0 >> 4) + nt) * 512;
            ushort4 st;
            st.x = f2bf(acc[ct][nt][0] + bvv);
            st.y = f2bf(acc[ct][nt][1] + bvv);
            st.z = f2bf(acc[ct][nt][2] + bvv);
            st.w = f2bf(acc[ct][nt][3] + bvv);
            *(ushort4*)(vbuf + fb + off + ct * 16 * 8) = st;
        }
    }
}

__device__ __forceinline__ void conv_qk_body(
        int cv, const unsigned short* __restrict__ xT, const unsigned short* __restrict__ wqkb,
        const float* __restrict__ bq, const float* __restrict__ bk,
        unsigned short* __restrict__ qrawh, unsigned short* __restrict__ krawh,
        float* __restrict__ nu2, int tid) {
    int wv_ = tid >> 6, lane = tid & 63;
    int q16 = lane >> 4, c16 = lane & 15;
    int nb2 = cv & 63, b = cv >> 6;
    int nl = nb2 * 64 + wv_ * 16 + c16;     // load-n (A-frag m index)
    int h = nl >> 6, w = nl & 63;
    bool vm1 = (w != 0), vp1 = (w != 63);
    bool vm64 = (h != 0), vp64 = (h != 63);
    short8 zero8 = {0, 0, 0, 0, 0, 0, 0, 0};
    floatx4 accq = {0.f, 0.f, 0.f, 0.f}, acck = {0.f, 0.f, 0.f, 0.f};
    const unsigned short* xb = xT + (size_t)b * NN * CC;
    const unsigned short* wrow = wqkb + c16 * 256;
    for (int kc = 0; kc < 8; ++kc) {
        int ko = kc * 32 + q16 * 8;
        short8 b0 = *(const short8*)(xb + (size_t)nl * CC + ko);
        short8 bm1 = vm1 ? *(const short8*)(xb + (size_t)(nl - 1) * CC + ko) : zero8;
        short8 bp1 = vp1 ? *(const short8*)(xb + (size_t)(nl + 1) * CC + ko) : zero8;
        short8 bm64 = vm64 ? *(const short8*)(xb + (size_t)(nl - 64) * CC + ko) : zero8;
        short8 bp64 = vp64 ? *(const short8*)(xb + (size_t)(nl + 64) * CC + ko) : zero8;
        short8 aq0 = *(const short8*)(wrow + 0 * 4096 + ko);
        short8 aq1 = *(const short8*)(wrow + 1 * 4096 + ko);
        short8 aq2 = *(const short8*)(wrow + 2 * 4096 + ko);
        short8 ak0 = *(const short8*)(wrow + 12288 + 0 * 4096 + ko);
        short8 ak1 = *(const short8*)(wrow + 12288 + 1 * 4096 + ko);
        short8 ak2 = *(const short8*)(wrow + 12288 + 2 * 4096 + ko);
        accq = __builtin_amdgcn_mfma_f32_16x16x32_bf16(bm1, aq0, accq, 0, 0, 0);
        accq = __builtin_amdgcn_mfma_f32_16x16x32_bf16(b0, aq1, accq, 0, 0, 0);
        accq = __builtin_amdgcn_mfma_f32_16x16x32_bf16(bp1, aq2, accq, 0, 0, 0);
        acck = __builtin_amdgcn_mfma_f32_16x16x32_bf16(bm64, ak0, acck, 0, 0, 0);
        acck = __builtin_amdgcn_mfma_f32_16x16x32_bf16(b0, ak1, acck, 0, 0, 0);
        acck = __builtin_amdgcn_mfma_f32_16x16x32_bf16(bp64, ak2, acck, 0, 0, 0);
    }
    // C: row = q16*4+r -> n, col = c16 -> o. bf16 ushort4 stores.
    int nst = nb2 * 64 + wv_ * 16 + q16 * 4;
    float bqv = bq[c16], bkv = bk[c16];
    ushort4 sq4, sk4;
    float ssq = 0.f, ssk = 0.f;
    {
        float vq0 = accq[0] + bqv, vq1 = accq[1] + bqv, vq2 = accq[2] + bqv, vq3 = accq[3] + bqv;
        float vk0 = acck[0] + bkv, vk1 = acck[1] + bkv, vk2 = acck[2] + bkv, vk3 = acck[3] + bkv;
        sq4.x = f2bf(vq0); sq4.y = f2bf(vq1); sq4.z = f2bf(vq2); sq4.w = f2bf(vq3);
        sk4.x = f2bf(vk0); sk4.y = f2bf(vk1); sk4.z = f2bf(vk2); sk4.w = f2bf(vk3);
        ssq = vq0 * vq0 + vq1 * vq1 + vq2 * vq2 + vq3 * vq3;
        ssk = vk0 * vk0 + vk1 * vk1 + vk2 * vk2 + vk3 * vk3;
    }
    *(ushort4*)(qrawh + (size_t)(b * C16 + c16) * NN + nst) = sq4;
    *(ushort4*)(krawh + (size_t)(b * C16 + c16) * NN + nst) = sk4;
    ssq += __shfl_xor(ssq, 16, 64);
    ssq += __shfl_xor(ssq, 32, 64);
    ssk += __shfl_xor(ssk, 16, 64);
    ssk += __shfl_xor(ssk, 32, 64);
    if (lane < 16) {
        atomicAdd(nu2 + b * C16 + lane, ssq);
        atomicAdd(nu2 + 64 + b * C16 + lane, ssk);
    }
}

// FRN + Mish. Mish via identity: tanh(softplus(v)) = (t^2+2t)/(t^2+2t+2), t=e^v.
__device__ __forceinline__ void frn_body(
        int blk, const unsigned short* __restrict__ qrawh, const unsigned short* __restrict__ krawh,
        const float* __restrict__ nu2, const float* __restrict__ eps_q,
        const float* __restrict__ eps_k, unsigned short* __restrict__ qb,
        unsigned short* __restrict__ kb, int tid) {
    int tensor = blk >> 8;
    int b = (blk >> 6) & 3;
    int nch = blk & 63;
    const unsigned short* raw = tensor ? krawh : qrawh;
    const float* eps = tensor ? eps_k : eps_q;
    unsigned short* outp = tensor ? kb : qb;
    const float* nu = nu2 + tensor * 64 + b * C16;
    float scale = tensor ? 1.0f : 1.44269504f;
    int n = nch * 64 + (tid & 63);
    int oq = tid >> 6;            // 0..3 -> channels oq*4..oq*4+3
    ushort4 pk4;
#pragma unroll
    for (int i = 0; i < 4; ++i) {
        int o = oq * 4 + i;
        float r = bf2f(raw[(size_t)(b * C16 + o) * NN + n]);
        float v = r * rsqrtf(nu[o] * (1.f / (float)NN) + fabsf(eps[o]));
        float t = EXP2(v * 1.44269504f);
        float num = t * t + 2.0f * t;
        float m = (v * num) * __builtin_amdgcn_rcpf(num + 2.0f);
        if (v > 30.f) m = v;
        m *= scale;
        ((unsigned short*)&pk4)[i] = f2bf(m);
    }
    size_t base = ((size_t)b * 128 + (n >> 5)) * 512 + (size_t)(n & 31) * 8
                + (size_t)(oq >> 1) * 256 + (oq & 1) * 4;
    *(ushort4*)(outp + base) = pk4;
}

// exp2 (NO shift — softmax is shift-invariant). Half-pack: 8 score elems -> one
// bf16 A-frag word via v_permlane32_swap_b32.
__device__ __forceinline__ void pack_half(
        const floatx16& sc, int h, short8* A, float* lsum) {
    unsigned pk[4];
    float ls = 0.f;
#pragma unroll
    for (int p = 0; p < 4; ++p) {
        float e0 = EXP2(sc[8 * h + 2 * p]);
        float e1 = EXP2(sc[8 * h + 2 * p + 1]);
        ls += e0 + e1;
        pk[p] = __builtin_amdgcn_perm(__float_as_uint(e1), __float_as_uint(e0), 0x07060302u);
    }
    *lsum += ls;
    asm("v_permlane32_swap_b32 %0, %1" : "+v"(pk[0]), "+v"(pk[2]));
    asm("v_permlane32_swap_b32 %0, %1" : "+v"(pk[1]), "+v"(pk[3]));
    union { unsigned u[4]; short8 s; } a;
    a.u[0] = pk[0]; a.u[1] = pk[1]; a.u[2] = pk[2]; a.u[3] = pk[3];
    *A = a.s;
}

// attention body: j=64 c=128 per block, split-pack interleaved (r3 structure, 49 us)
__device__ __forceinline__ void attn_body(
        int id, const unsigned short* __restrict__ qb, const unsigned short* __restrict__ kb,
        const unsigned short* __restrict__ vbuf, const float* __restrict__ x,
        const float* __restrict__ gamma_p, float* __restrict__ out,
        float (*lpart)[2][32], float (*obuf)[32][33], int tid) {
    int wv_ = __builtin_amdgcn_readfirstlane(tid >> 6);
    int lane = tid & 63;
    int l31 = lane & 31, lh = lane >> 5;
    int cs = id & 1, b = (id >> 1) & 3, jt = id >> 3;
    int jbase = jt * 64, cb = cs * 128;
    int lane8 = lane * 8;

    const unsigned short* qfb = qb + ((size_t)b * 128 + (jbase >> 5)) * 512 + lane8;
    const unsigned short* kfb = kb + ((size_t)b * 128 + (wv_ * 32)) * 512 + lane8;

    short8 qf0 = *(const short8*)qfb;
    short8 qf1 = *(const short8*)(qfb + 512);

    floatx16 z16 = {0,0,0,0,0,0,0,0,0,0,0,0,0,0,0,0};
    floatx16 acc0[4], acc1[4];
#pragma unroll
    for (int cg = 0; cg < 4; ++cg) { acc0[cg] = z16; acc1[cg] = z16; }
    float lsum0 = 0.f, lsum1 = 0.f;

    const unsigned short* vp0 = vbuf + (((size_t)b * 8 + cs * 4 + 0) * 256 + wv_ * 64) * 512 + lane8;
    const unsigned short* vp1 = vbuf + (((size_t)b * 8 + cs * 4 + 1) * 256 + wv_ * 64) * 512 + lane8;
    const unsigned short* vp2 = vbuf + (((size_t)b * 8 + cs * 4 + 2) * 256 + wv_ * 64) * 512 + lane8;
    const unsigned short* vp3 = vbuf + (((size_t)b * 8 + cs * 4 + 3) * 256 + wv_ * 64) * 512 + lane8;

    short8 ak = *(const short8*)kfb;
#pragma unroll 1
    for (int step = 0; step < 32; ++step) {
        short8 vf0a = *(const short8*)vp0;
        short8 vf1a = *(const short8*)vp1;
        short8 vf2a = *(const short8*)vp2;
        short8 vf3a = *(const short8*)vp3;
        short8 vf0b = *(const short8*)(vp0 + 512);
        short8 vf1b = *(const short8*)(vp1 + 512);
        short8 vf2b = *(const short8*)(vp2 + 512);
        short8 vf3b = *(const short8*)(vp3 + 512);
        floatx16 sc0 = __builtin_amdgcn_mfma_f32_32x32x16_bf16(ak, qf0, z16, 0, 0, 0);
        floatx16 sc1 = __builtin_amdgcn_mfma_f32_32x32x16_bf16(ak, qf1, z16, 0, 0, 0);
        ak = *(const short8*)(kfb + (size_t)((step + 1) & 31) * 512);
        short8 A;
        pack_half(sc0, 0, &A, &lsum0);                 // A00
        __builtin_amdgcn_s_setprio(1);
        acc0[0] = __builtin_amdgcn_mfma_f32_32x32x16_bf16(A, vf0a, acc0[0], 0, 0, 0);
        acc0[1] = __builtin_amdgcn_mfma_f32_32x32x16_bf16(A, vf1a, acc0[1], 0, 0, 0);
        acc0[2] = __builtin_amdgcn_mfma_f32_32x32x16_bf16(A, vf2a, acc0[2], 0, 0, 0);
        acc0[3] = __builtin_amdgcn_mfma_f32_32x32x16_bf16(A, vf3a, acc0[3], 0, 0, 0);
        __builtin_amdgcn_s_setprio(0);
        __builtin_amdgcn_sched_barrier(0);
        pack_half(sc0, 1, &A, &lsum0);                 // A01
        __builtin_amdgcn_s_setprio(1);
        acc0[0] = __builtin_amdgcn_mfma_f32_32x32x16_bf16(A, vf0b, acc0[0], 0, 0, 0);
        acc0[1] = __builtin_amdgcn_mfma_f32_32x32x16_bf16(A, vf1b, acc0[1], 0, 0, 0);
        acc0[2] = __builtin_amdgcn_mfma_f32_32x32x16_bf16(A, vf2b, acc0[2], 0, 0, 0);
        acc0[3] = __builtin_amdgcn_mfma_f32_32x32x16_bf16(A, vf3b, acc0[3], 0, 0, 0);
        __builtin_amdgcn_s_setprio(0);
        __builtin_amdgcn_sched_barrier(0);
        pack_half(sc1, 0, &A, &lsum1);                 // A10
        __builtin_amdgcn_s_setprio(1);
        acc1[0] = __builtin_amdgcn_mfma_f32_32x32x16_bf16(A, vf0a, acc1[0], 0, 0, 0);
        acc1[1] = __builtin_amdgcn_mfma_f32_32x32x16_bf16(A, vf1a, acc1[1], 0, 0, 0);
        acc1[2] = __builtin_amdgcn_mfma_f32_32x32x16_bf16(A, vf2a, acc1[2], 0, 0, 0);
        acc1[3] = __builtin_amdgcn_mfma_f32_32x32x16_bf16(A, vf3a, acc1[3], 0, 0, 0);
        __builtin_amdgcn_s_setprio(0);
        __builtin_amdgcn_sched_barrier(0);
        pack_half(sc1, 1, &A, &lsum1);                 // A11
        __builtin_amdgcn_s_setprio(1);
        acc1[0] = __builtin_amdgcn_mfma_f32_32x32x16_bf16(A, vf0b, acc1[0], 0, 0, 0);
        acc1[1] = __builtin_amdgcn_mfma_f32_32x32x16_bf16(A, vf1b, acc1[1], 0, 0, 0);
        acc1[2] = __builtin_amdgcn_mfma_f32_32x32x16_bf16(A, vf2b, acc1[2], 0, 0, 0);
        acc1[3] = __builtin_amdgcn_mfma_f32_32x32x16_bf16(A, vf3b, acc1[3], 0, 0, 0);
        __builtin_amdgcn_s_setprio(0);
        vp0 += 1024; vp1 += 1024; vp2 += 1024; vp3 += 1024;
    }

    lsum0 += __shfl_xor(lsum0, 32, 64);
    lsum1 += __shfl_xor(lsum1, 32, 64);
    if (lh == 0) { lpart[wv_][0][l31] = lsum0; lpart[wv_][1][l31] = lsum1; }
    __syncthreads();

    int j31 = tid & 31;
    float gamma = gamma_p[0];
    float gl0 = gamma / (lpart[0][0][j31] + lpart[1][0][j31] + lpart[2][0][j31] + lpart[3][0][j31]);
    float gl1 = gamma / (lpart[0][1][j31] + lpart[1][1][j31] + lpart[2][1][j31] + lpart[3][1][j31]);
    const float* xbb = x + (size_t)b * CC * NN;
    float* obb = out + (size_t)b * CC * NN;
    int hofs = lh * 4;
    int cgrp = tid >> 5;
#pragma unroll
    for (int jg = 0; jg < 2; ++jg) {
        float gl = jg ? gl1 : gl0;
#pragma unroll
        for (int cg = 0; cg < 4; ++cg) {
            __syncthreads();
            const floatx16& a = jg ? acc1[cg] : acc0[cg];
#pragma unroll
            for (int r = 0; r < 16; ++r) {
                int row = (r & 3) + 8 * (r >> 2) + hofs;
                obuf[wv_][row][l31] = a[r];
            }
            __syncthreads();
#pragma unroll
            for (int i = 0; i < 4; ++i) {
                int c = cgrp * 4 + i;
                float val = obuf[0][j31][c] + obuf[1][j31][c] + obuf[2][j31][c] + obuf[3][j31][c];
                size_t oidx = (size_t)(cb + cg * 32 + c) * NN + jbase + jg * 32 + j31;
                obb[oidx] = fmaf(gl, val, xbb[oidx]);
            }
        }
    }
}

// ================= mega cooperative kernel: all 4 phases, grid 512x256 ==========
__global__ __launch_bounds__(256, 2) void mega_kernel(
        const float* __restrict__ x, const float* __restrict__ wq,
        const float* __restrict__ bq, const float* __restrict__ wk,
        const float* __restrict__ bk, const float* __restrict__ wv,
        const float* __restrict__ bv, const float* __restrict__ gamma_p,
        const float* __restrict__ eps_q, const float* __restrict__ eps_k,
        float* __restrict__ out, char* __restrict__ ws) {
    // LDS union: prep tile (64x65 f32 = 16640B) / attn lpart(1024B)+obuf(16896B)
    __shared__ __align__(16) char smem_u[17920];
    float (*tile_t)[65] = (float (*)[65])smem_u;
    float (*lpart)[2][32] = (float (*)[2][32])smem_u;
    float (*obuf)[32][33] = (float (*)[32][33])(smem_u + 1024);

    unsigned short* qrawh = (unsigned short*)ws;
    unsigned short* krawh = (unsigned short*)(ws + (1u << 20));
    float* nu2  = (float*)(ws + (2u << 20));
    unsigned short* qb = (unsigned short*)(ws + (2u << 20) + 4096);
    unsigned short* kb = qb + (size_t)NB * NN * C16;
    unsigned short* vbuf = kb + (size_t)NB * NN * C16;
    unsigned short* xT = vbuf + (size_t)NB * CC * NN;
    unsigned short* wvb = xT + (size_t)NB * NN * CC;
    unsigned short* wqkb = wvb + (size_t)CC * CC;

    cg::grid_group grid = cg::this_grid();
    int bid = blockIdx.x;
    int tid = threadIdx.x;

    // ---- phase P: transpose x -> xT (2 tiles/block) + weight cast + nu2 zero ----
    {
        prep_tile_body(bid, x, xT, tile_t, tid);
        __syncthreads();                       // protect LDS reuse
        prep_tile_body(bid + 512, x, xT, tile_t, tid);
        if (bid < 88) prep_wt_body(bid + 1024, wv, wq, wk, wvb, wqkb, nu2, tid);
    }
    __threadfence();
    grid.sync();
    __threadfence();

    // ---- phase C: conv_v (all blocks) + conv_qk (blocks < 256) ----
    {
        conv_v_body(bid, xT, wvb, bv, vbuf, tid);
        if (bid < 256) conv_qk_body(bid, xT, wqkb, bq, bk, qrawh, krawh, nu2, tid);
    }
    __threadfence();
    grid.sync();
    __threadfence();

    // ---- phase F: FRN + Mish ----
    frn_body(bid, qrawh, krawh, nu2, eps_q, eps_k, qb, kb, tid);
    __threadfence();
    grid.sync();
    __threadfence();

    // ---- phase A: attention ----
    __syncthreads();                           // LDS handoff tile_t -> lpart/obuf
    attn_body(bid, qb, kb, vbuf, x, gamma_p, out, lpart, obuf, tid);
}

// ================= fallback 4-kernel path (r6 baseline, proven) ==========
__global__ __launch_bounds__(256) void prep_kernel(
        const float* __restrict__ x, const float* __restrict__ wv,
        const float* __restrict__ wq, const float* __restrict__ wk,
        unsigned short* __restrict__ xT, unsigned short* __restrict__ wvb,
        unsigned short* __restrict__ wqkb, float* __restrict__ nu2) {
    __shared__ float tile_t[64][65];
    int bid = blockIdx.x;
    if (bid < 1024) prep_tile_body(bid, x, xT, tile_t, threadIdx.x);
    else prep_wt_body(bid, wv, wq, wk, wvb, wqkb, nu2, threadIdx.x);
}

__global__ __launch_bounds__(256) void conv_kernel(
        const unsigned short* __restrict__ xT, const unsigned short* __restrict__ wvb,
        const unsigned short* __restrict__ wqkb, const float* __restrict__ bv,
        const float* __restrict__ bq, const float* __restrict__ bk,
        unsigned short* __restrict__ vbuf, unsigned short* __restrict__ qrawh,
        unsigned short* __restrict__ krawh, float* __restrict__ nu2) {
    int bid = blockIdx.x;
    if (bid < 512) conv_v_body(bid, xT, wvb, bv, vbuf, threadIdx.x);
    else conv_qk_body(bid - 512, xT, wqkb, bq, bk, qrawh, krawh, nu2, threadIdx.x);
}

__global__ __launch_bounds__(256) void frn_mish_kernel(
        const unsigned short* __restrict__ qrawh, const unsigned short* __restrict__ krawh,
        const float* __restrict__ nu2, const float* __restrict__ eps_q,
        const float* __restrict__ eps_k, unsigned short* __restrict__ qb,
        unsigned short* __restrict__ kb) {
    frn_body(blockIdx.x, qrawh, krawh, nu2, eps_q, eps_k, qb, kb, threadIdx.x);
}

__global__ __launch_bounds__(256, 2) void attn_kernel(
        const unsigned short* __restrict__ qb, const unsigned short* __restrict__ kb,
        const unsigned short* __restrict__ vbuf, const float* __restrict__ x,
        const float* __restrict__ gamma_p, float* __restrict__ out) {
    __shared__ float lpart[4][2][32];
    __shared__ float obuf[4][32][33];
    attn_body(blockIdx.x, qb, kb, vbuf, x, gamma_p, out, lpart, obuf, threadIdx.x);
}

extern "C" void kernel_launch(void* const* d_in, const int* in_sizes, int n_in,
                              void* d_out, int out_size, void* d_ws, size_t ws_size,
                              hipStream_t stream) {
    const float* x     = (const float*)d_in[0];
    const float* wq    = (const float*)d_in[1];
    const float* bq    = (const float*)d_in[2];
    const float* wk    = (const float*)d_in[3];
    const float* bk    = (const float*)d_in[4];
    const float* wv    = (const float*)d_in[5];
    const float* bv    = (const float*)d_in[6];
    const float* gamma = (const float*)d_in[7];
    const float* eps_q = (const float*)d_in[8];
    const float* eps_k = (const float*)d_in[9];
    float* out = (float*)d_out;
    char* ws = (char*)d_ws;

    static int coop_ok = -1;
    if (coop_ok < 0) {
        int v = 0;
        if (hipDeviceGetAttribute(&v, hipDeviceAttributeCooperativeLaunch, 0) != hipSuccess) v = 0;
        coop_ok = v;
    }

    if (coop_ok) {
        void* args[] = {(void*)&x, (void*)&wq, (void*)&bq, (void*)&wk, (void*)&bk,
                        (void*)&wv, (void*)&bv, (void*)&gamma, (void*)&eps_q,
                        (void*)&eps_k, (void*)&out, (void*)&ws};
        hipError_t err = hipLaunchCooperativeKernel(
            (void*)mega_kernel, dim3(512), dim3(256), args, 0, stream);
        if (err == hipSuccess) return;
        coop_ok = 0;   // fall through to 4-kernel path
    }

    unsigned short* qrawh = (unsigned short*)ws;
    unsigned short* krawh = (unsigned short*)(ws + (1u << 20));
    float* nu2  = (float*)(ws + (2u << 20));
    unsigned short* qb = (unsigned short*)(ws + (2u << 20) + 4096);
    unsigned short* kb = qb + (size_t)NB * NN * C16;
    unsigned short* vbuf = kb + (size_t)NB * NN * C16;
    unsigned short* xT = vbuf + (size_t)NB * CC * NN;
    unsigned short* wvb = xT + (size_t)NB * NN * CC;
    unsigned short* wqkb = wvb + (size_t)CC * CC;

    prep_kernel<<<dim3(1112), dim3(256), 0, stream>>>(x, wv, wq, wk, xT, wvb, wqkb, nu2);
    conv_kernel<<<dim3(768), dim3(256), 0, stream>>>(xT, wvb, wqkb, bv, bq, bk, vbuf, qrawh, krawh, nu2);
    frn_mish_kernel<<<dim3(512), dim3(256), 0, stream>>>(qrawh, krawh, nu2, eps_q, eps_k, qb, kb);
    attn_kernel<<<dim3(512), dim3(256), 0, stream>>>(qb, kb, vbuf, x, gamma, out);
}